// Round 1
// baseline (1240.245 us; speedup 1.0000x reference)
//
#include <hip/hip_runtime.h>
#include <math.h>

#define EMBED 64

// out[0] = h0 (layer-0 embedding), straight float4 copy
__global__ void copy_h0_kernel(const float* __restrict__ h0, float* __restrict__ out, int n4) {
    int i = blockIdx.x * blockDim.x + threadIdx.x;
    if (i < n4) ((float4*)out)[i] = ((const float4*)h0)[i];
}

// edge_row is sorted ascending -> build CSR row_ptr[N+1] by boundary scatter
__global__ void build_rowptr_kernel(const int* __restrict__ row, int* __restrict__ rp, int E, int N) {
    int i = blockIdx.x * blockDim.x + threadIdx.x;
    if (i >= E) return;
    if (i == 0) {
        int r0 = row[0];
        for (int r = 0; r <= r0; ++r) rp[r] = 0;
    } else {
        int a = row[i - 1], b = row[i];
        for (int r = a + 1; r <= b; ++r) rp[r] = i;
    }
    if (i == E - 1) {
        int rl = row[E - 1];
        for (int r = rl + 1; r <= N; ++r) rp[r] = E;
    }
}

// one wave per edge: logits[e] = dot(h_att[row[e]], t_att[col[e]])
__global__ void edge_logits_kernel(const float* __restrict__ ha, const float* __restrict__ ta,
                                   const int* __restrict__ row, const int* __restrict__ col,
                                   float* __restrict__ logits, int E) {
    int e = blockIdx.x * (blockDim.x >> 6) + (threadIdx.x >> 6);
    int lane = threadIdx.x & 63;
    if (e >= E) return;
    int r = row[e];
    int c = col[e];
    float p = ha[(size_t)r * EMBED + lane] * ta[(size_t)c * EMBED + lane];
    #pragma unroll
    for (int off = 32; off > 0; off >>= 1) p += __shfl_xor(p, off);
    if (lane == 0) logits[e] = p;
}

// one thread per node: softmax over its CSR range, in-place logits -> weights
__global__ void node_softmax_kernel(const int* __restrict__ rp, float* __restrict__ lw, int N) {
    int n = blockIdx.x * blockDim.x + threadIdx.x;
    if (n >= N) return;
    int s = rp[n], t = rp[n + 1];
    if (s >= t) return;
    float m = -INFINITY;
    for (int e = s; e < t; ++e) m = fmaxf(m, lw[e]);
    float sum = 0.f;
    for (int e = s; e < t; ++e) sum += expf(lw[e] - m);
    float inv = 1.f / fmaxf(sum, 1e-12f);
    for (int e = s; e < t; ++e) lw[e] = expf(lw[e] - m) * inv;
}

// one wave per node (grid-stride): msg = sum_e w_e * h[col_e]; add = h[n]+msg;
// x = relu(add @ W^T + b); out = x / max(||x||, eps)
// Lane i holds feature i; W row i lives in 64 VGPRs of lane i; add[j] broadcast via shfl.
__global__ void __launch_bounds__(256) prop_layer_kernel(
        const float* __restrict__ h_in,
        const float* __restrict__ W, const float* __restrict__ b,
        const int* __restrict__ col, const float* __restrict__ ew,
        const int* __restrict__ rp,
        float* __restrict__ out, int N, int totalWaves) {
    int wid = (blockIdx.x * blockDim.x + threadIdx.x) >> 6;
    int lane = threadIdx.x & 63;

    // lane i loads W[i][0..63] into registers (16 KB total, L1-resident after first wave)
    float4 Wr[16];
    const float4* W4 = (const float4*)W;
    #pragma unroll
    for (int q = 0; q < 16; ++q) Wr[q] = W4[lane * 16 + q];
    float bias = b[lane];

    for (int n = wid; n < N; n += totalWaves) {
        int s = rp[n], t = rp[n + 1];
        float acc = 0.f;
        for (int e = s; e < t; ++e) {
            int c = col[e];
            float wgt = ew[e];
            acc = fmaf(wgt, h_in[(size_t)c * EMBED + lane], acc);
        }
        float addv = h_in[(size_t)n * EMBED + lane] + acc;

        float x = bias;
        #pragma unroll
        for (int j = 0; j < 16; ++j) {
            float4 wv = Wr[j];
            x = fmaf(__shfl(addv, 4 * j + 0), wv.x, x);
            x = fmaf(__shfl(addv, 4 * j + 1), wv.y, x);
            x = fmaf(__shfl(addv, 4 * j + 2), wv.z, x);
            x = fmaf(__shfl(addv, 4 * j + 3), wv.w, x);
        }
        x = fmaxf(x, 0.f);

        float ss = x * x;
        #pragma unroll
        for (int off = 32; off > 0; off >>= 1) ss += __shfl_xor(ss, off);
        float nrm = sqrtf(ss);
        float scale = 1.f / fmaxf(nrm, 1e-12f);
        out[(size_t)n * EMBED + lane] = x * scale;
    }
}

extern "C" void kernel_launch(void* const* d_in, const int* in_sizes, int n_in,
                              void* d_out, int out_size, void* d_ws, size_t ws_size,
                              hipStream_t stream) {
    const float* h0   = (const float*)d_in[0];
    const float* ha   = (const float*)d_in[1];
    const float* ta   = (const float*)d_in[2];
    const float* w1   = (const float*)d_in[3];
    const float* b1   = (const float*)d_in[4];
    const float* w2   = (const float*)d_in[5];
    const float* b2   = (const float*)d_in[6];
    const int*   erow = (const int*)d_in[7];
    const int*   ecol = (const int*)d_in[8];

    const int N = in_sizes[0] / EMBED;
    const int E = in_sizes[7];
    float* out = (float*)d_out;

    // workspace layout: row_ptr[N+1] ints, then edge weights[E] floats
    int*   rp = (int*)d_ws;
    size_t rp_bytes = ((size_t)(N + 1) * sizeof(int) + 255) & ~(size_t)255;
    float* ew = (float*)((char*)d_ws + rp_bytes);

    // 1. out[0] = h0
    {
        int n4 = N * EMBED / 4;
        copy_h0_kernel<<<(n4 + 255) / 256, 256, 0, stream>>>(h0, out, n4);
    }
    // 2. CSR row_ptr
    build_rowptr_kernel<<<(E + 255) / 256, 256, 0, stream>>>(erow, rp, E, N);
    // 3. edge logits (one wave/edge)
    {
        int edges_per_block = 256 / 64;
        int blocks = (E + edges_per_block - 1) / edges_per_block;
        edge_logits_kernel<<<blocks, 256, 0, stream>>>(ha, ta, erow, ecol, ew, E);
    }
    // 4. per-node softmax (in-place logits -> weights)
    node_softmax_kernel<<<(N + 255) / 256, 256, 0, stream>>>(rp, ew, N);

    // 5. layer 1: h0 -> out[1];  layer 2: out[1] -> out[2]
    const int blocks = 2048;
    const int totalWaves = blocks * (256 / 64);
    float* out1 = out + (size_t)N * EMBED;
    float* out2 = out + 2 * (size_t)N * EMBED;
    prop_layer_kernel<<<blocks, 256, 0, stream>>>(h0,   w1, b1, ecol, ew, rp, out1, N, totalWaves);
    prop_layer_kernel<<<blocks, 256, 0, stream>>>(out1, w2, b2, ecol, ew, rp, out2, N, totalWaves);
}

// Round 2
// 1017.150 us; speedup vs baseline: 1.2193x; 1.2193x over previous
//
#include <hip/hip_runtime.h>
#include <math.h>

#define EMBED 64

// out[0] = h0 (layer-0 embedding), straight float4 copy
__global__ void copy_h0_kernel(const float* __restrict__ h0, float* __restrict__ out, int n4) {
    int i = blockIdx.x * blockDim.x + threadIdx.x;
    if (i < n4) ((float4*)out)[i] = ((const float4*)h0)[i];
}

// edge_row is sorted ascending -> build CSR row_ptr[N+1] by boundary scatter
__global__ void build_rowptr_kernel(const int* __restrict__ row, int* __restrict__ rp, int E, int N) {
    int i = blockIdx.x * blockDim.x + threadIdx.x;
    if (i >= E) return;
    if (i == 0) {
        int r0 = row[0];
        for (int r = 0; r <= r0; ++r) rp[r] = 0;
    } else {
        int a = row[i - 1], b = row[i];
        for (int r = a + 1; r <= b; ++r) rp[r] = i;
    }
    if (i == E - 1) {
        int rl = row[E - 1];
        for (int r = rl + 1; r <= N; ++r) rp[r] = E;
    }
}

// one LANE per edge: logits[e] = dot(h_att[row[e]], t_att[col[e]])
// Sorted rows => adjacent lanes hit the same ha row (L1 broadcast); ta is the
// random gather but each lane streams 256 contiguous bytes via dwordx4.
__global__ void __launch_bounds__(256) edge_logits_kernel(
        const float* __restrict__ ha, const float* __restrict__ ta,
        const int* __restrict__ row, const int* __restrict__ col,
        float* __restrict__ logits, int E) {
    int e = blockIdx.x * blockDim.x + threadIdx.x;
    if (e >= E) return;
    const float4* ha4 = (const float4*)(ha + (size_t)row[e] * EMBED);
    const float4* ta4 = (const float4*)(ta + (size_t)col[e] * EMBED);
    float4 acc = make_float4(0.f, 0.f, 0.f, 0.f);
    #pragma unroll
    for (int q = 0; q < 16; ++q) {
        float4 a = ha4[q];
        float4 t = ta4[q];
        acc.x = fmaf(a.x, t.x, acc.x);
        acc.y = fmaf(a.y, t.y, acc.y);
        acc.z = fmaf(a.z, t.z, acc.z);
        acc.w = fmaf(a.w, t.w, acc.w);
    }
    logits[e] = (acc.x + acc.y) + (acc.z + acc.w);
}

// one WAVE per node: softmax over CSR range, in-place logits -> weights.
// Fast path (degree <= 64): logits live in one register, exp computed once.
__global__ void __launch_bounds__(256) node_softmax_kernel(
        const int* __restrict__ rp, float* __restrict__ lw, int N) {
    int n = (blockIdx.x * blockDim.x + threadIdx.x) >> 6;
    int lane = threadIdx.x & 63;
    if (n >= N) return;
    int s = rp[n], t = rp[n + 1];
    int deg = t - s;
    if (deg <= 0) return;

    if (deg <= 64) {
        float v = (lane < deg) ? lw[s + lane] : -INFINITY;
        float m = v;
        #pragma unroll
        for (int off = 32; off > 0; off >>= 1) m = fmaxf(m, __shfl_xor(m, off));
        float e = (lane < deg) ? expf(v - m) : 0.f;
        float sum = e;
        #pragma unroll
        for (int off = 32; off > 0; off >>= 1) sum += __shfl_xor(sum, off);
        float inv = 1.f / fmaxf(sum, 1e-12f);
        if (lane < deg) lw[s + lane] = e * inv;
    } else {
        float m = -INFINITY;
        for (int e = s + lane; e < t; e += 64) m = fmaxf(m, lw[e]);
        #pragma unroll
        for (int off = 32; off > 0; off >>= 1) m = fmaxf(m, __shfl_xor(m, off));
        float sum = 0.f;
        for (int e = s + lane; e < t; e += 64) sum += expf(lw[e] - m);
        #pragma unroll
        for (int off = 32; off > 0; off >>= 1) sum += __shfl_xor(sum, off);
        float inv = 1.f / fmaxf(sum, 1e-12f);
        for (int e = s + lane; e < t; e += 64) lw[e] = expf(lw[e] - m) * inv;
    }
}

// one wave per node (grid-stride): msg = sum_e w_e * h[col_e]; add = h[n]+msg;
// x = relu(add @ W^T + b); out = x / max(||x||, eps)
// Lane i holds feature i; W row i lives in 64 VGPRs of lane i; add[j] broadcast via shfl.
__global__ void __launch_bounds__(256) prop_layer_kernel(
        const float* __restrict__ h_in,
        const float* __restrict__ W, const float* __restrict__ b,
        const int* __restrict__ col, const float* __restrict__ ew,
        const int* __restrict__ rp,
        float* __restrict__ out, int N, int totalWaves) {
    int wid = (blockIdx.x * blockDim.x + threadIdx.x) >> 6;
    int lane = threadIdx.x & 63;

    // lane i loads W[i][0..63] into registers (16 KB total, L1-resident after first wave)
    float4 Wr[16];
    const float4* W4 = (const float4*)W;
    #pragma unroll
    for (int q = 0; q < 16; ++q) Wr[q] = W4[lane * 16 + q];
    float bias = b[lane];

    for (int n = wid; n < N; n += totalWaves) {
        int s = rp[n], t = rp[n + 1];
        float acc = 0.f;
        for (int e = s; e < t; ++e) {
            int c = col[e];
            float wgt = ew[e];
            acc = fmaf(wgt, h_in[(size_t)c * EMBED + lane], acc);
        }
        float addv = h_in[(size_t)n * EMBED + lane] + acc;

        float x = bias;
        #pragma unroll
        for (int j = 0; j < 16; ++j) {
            float4 wv = Wr[j];
            x = fmaf(__shfl(addv, 4 * j + 0), wv.x, x);
            x = fmaf(__shfl(addv, 4 * j + 1), wv.y, x);
            x = fmaf(__shfl(addv, 4 * j + 2), wv.z, x);
            x = fmaf(__shfl(addv, 4 * j + 3), wv.w, x);
        }
        x = fmaxf(x, 0.f);

        float ss = x * x;
        #pragma unroll
        for (int off = 32; off > 0; off >>= 1) ss += __shfl_xor(ss, off);
        float nrm = sqrtf(ss);
        float scale = 1.f / fmaxf(nrm, 1e-12f);
        out[(size_t)n * EMBED + lane] = x * scale;
    }
}

extern "C" void kernel_launch(void* const* d_in, const int* in_sizes, int n_in,
                              void* d_out, int out_size, void* d_ws, size_t ws_size,
                              hipStream_t stream) {
    const float* h0   = (const float*)d_in[0];
    const float* ha   = (const float*)d_in[1];
    const float* ta   = (const float*)d_in[2];
    const float* w1   = (const float*)d_in[3];
    const float* b1   = (const float*)d_in[4];
    const float* w2   = (const float*)d_in[5];
    const float* b2   = (const float*)d_in[6];
    const int*   erow = (const int*)d_in[7];
    const int*   ecol = (const int*)d_in[8];

    const int N = in_sizes[0] / EMBED;
    const int E = in_sizes[7];
    float* out = (float*)d_out;

    // workspace layout: row_ptr[N+1] ints, then edge weights[E] floats
    int*   rp = (int*)d_ws;
    size_t rp_bytes = ((size_t)(N + 1) * sizeof(int) + 255) & ~(size_t)255;
    float* ew = (float*)((char*)d_ws + rp_bytes);

    // 1. out[0] = h0
    {
        int n4 = N * EMBED / 4;
        copy_h0_kernel<<<(n4 + 255) / 256, 256, 0, stream>>>(h0, out, n4);
    }
    // 2. CSR row_ptr
    build_rowptr_kernel<<<(E + 255) / 256, 256, 0, stream>>>(erow, rp, E, N);
    // 3. edge logits (one lane/edge)
    edge_logits_kernel<<<(E + 255) / 256, 256, 0, stream>>>(ha, ta, erow, ecol, ew, E);
    // 4. per-node softmax (one wave/node, in-place logits -> weights)
    {
        int waves_per_block = 256 / 64;
        int blocks = (N + waves_per_block - 1) / waves_per_block;
        node_softmax_kernel<<<blocks, 256, 0, stream>>>(rp, ew, N);
    }

    // 5. layer 1: h0 -> out[1];  layer 2: out[1] -> out[2]
    const int blocks = 2048;
    const int totalWaves = blocks * (256 / 64);
    float* out1 = out + (size_t)N * EMBED;
    float* out2 = out + 2 * (size_t)N * EMBED;
    prop_layer_kernel<<<blocks, 256, 0, stream>>>(h0,   w1, b1, ecol, ew, rp, out1, N, totalWaves);
    prop_layer_kernel<<<blocks, 256, 0, stream>>>(out1, w2, b2, ecol, ew, rp, out2, N, totalWaves);
}

// Round 3
// 729.667 us; speedup vs baseline: 1.6997x; 1.3940x over previous
//
#include <hip/hip_runtime.h>
#include <math.h>

#define EMBED 64

// out[0] = h0 (layer-0 embedding), straight float4 copy
__global__ void copy_h0_kernel(const float* __restrict__ h0, float* __restrict__ out, int n4) {
    int i = blockIdx.x * blockDim.x + threadIdx.x;
    if (i < n4) ((float4*)out)[i] = ((const float4*)h0)[i];
}

// edge_row is sorted ascending -> build CSR row_ptr[N+1] by boundary scatter
__global__ void build_rowptr_kernel(const int* __restrict__ row, int* __restrict__ rp, int E, int N) {
    int i = blockIdx.x * blockDim.x + threadIdx.x;
    if (i >= E) return;
    if (i == 0) {
        int r0 = row[0];
        for (int r = 0; r <= r0; ++r) rp[r] = 0;
    } else {
        int a = row[i - 1], b = row[i];
        for (int r = a + 1; r <= b; ++r) rp[r] = i;
    }
    if (i == E - 1) {
        int rl = row[E - 1];
        for (int r = rl + 1; r <= N; ++r) rp[r] = E;
    }
}

// one LANE per edge: logits[e] = dot(h_att[row[e]], t_att[col[e]])
__global__ void __launch_bounds__(256) edge_logits_kernel(
        const float* __restrict__ ha, const float* __restrict__ ta,
        const int* __restrict__ row, const int* __restrict__ col,
        float* __restrict__ logits, int E) {
    int e = blockIdx.x * blockDim.x + threadIdx.x;
    if (e >= E) return;
    const float4* ha4 = (const float4*)(ha + (size_t)row[e] * EMBED);
    const float4* ta4 = (const float4*)(ta + (size_t)col[e] * EMBED);
    float4 acc = make_float4(0.f, 0.f, 0.f, 0.f);
    #pragma unroll
    for (int q = 0; q < 16; ++q) {
        float4 a = ha4[q];
        float4 t = ta4[q];
        acc.x = fmaf(a.x, t.x, acc.x);
        acc.y = fmaf(a.y, t.y, acc.y);
        acc.z = fmaf(a.z, t.z, acc.z);
        acc.w = fmaf(a.w, t.w, acc.w);
    }
    logits[e] = (acc.x + acc.y) + (acc.z + acc.w);
}

// one WAVE per node: softmax over CSR range, in-place logits -> weights.
__global__ void __launch_bounds__(256) node_softmax_kernel(
        const int* __restrict__ rp, float* __restrict__ lw, int N) {
    int n = (blockIdx.x * blockDim.x + threadIdx.x) >> 6;
    int lane = threadIdx.x & 63;
    if (n >= N) return;
    int s = rp[n], t = rp[n + 1];
    int deg = t - s;
    if (deg <= 0) return;

    if (deg <= 64) {
        float v = (lane < deg) ? lw[s + lane] : -INFINITY;
        float m = v;
        #pragma unroll
        for (int off = 32; off > 0; off >>= 1) m = fmaxf(m, __shfl_xor(m, off));
        float e = (lane < deg) ? expf(v - m) : 0.f;
        float sum = e;
        #pragma unroll
        for (int off = 32; off > 0; off >>= 1) sum += __shfl_xor(sum, off);
        float inv = 1.f / fmaxf(sum, 1e-12f);
        if (lane < deg) lw[s + lane] = e * inv;
    } else {
        float m = -INFINITY;
        for (int e = s + lane; e < t; e += 64) m = fmaxf(m, lw[e]);
        #pragma unroll
        for (int off = 32; off > 0; off >>= 1) m = fmaxf(m, __shfl_xor(m, off));
        float sum = 0.f;
        for (int e = s + lane; e < t; e += 64) sum += expf(lw[e] - m);
        #pragma unroll
        for (int off = 32; off > 0; off >>= 1) sum += __shfl_xor(sum, off);
        float inv = 1.f / fmaxf(sum, 1e-12f);
        for (int e = s + lane; e < t; e += 64) lw[e] = expf(lw[e] - m) * inv;
    }
}

// one wave per node (grid-stride): msg = sum_e w_e * h[col_e]; add = h[n]+msg;
// x = relu(add @ W^T + b); out = x / max(||x||, eps)
// Edge gather loop unrolled x8/x4 so up to 8 gathers are in flight per wave
// (latency-bound fix: VALUBusy was 14%, both pipes idle).
__global__ void __launch_bounds__(256) prop_layer_kernel(
        const float* __restrict__ h_in,
        const float* __restrict__ W, const float* __restrict__ b,
        const int* __restrict__ col, const float* __restrict__ ew,
        const int* __restrict__ rp,
        float* __restrict__ out, int N, int totalWaves) {
    int wid = (blockIdx.x * blockDim.x + threadIdx.x) >> 6;
    int lane = threadIdx.x & 63;

    // lane i holds W[i][0..63] in 64 VGPRs
    float4 Wr[16];
    const float4* W4 = (const float4*)W;
    #pragma unroll
    for (int q = 0; q < 16; ++q) Wr[q] = W4[lane * 16 + q];
    float bias = b[lane];

    for (int n = wid; n < N; n += totalWaves) {
        int s = rp[n], t = rp[n + 1];
        float self = h_in[(size_t)n * EMBED + lane];  // overlaps with gathers below

        float acc0 = 0.f, acc1 = 0.f, acc2 = 0.f, acc3 = 0.f;
        int e = s;
        for (; e + 8 <= t; e += 8) {
            int c0 = col[e+0], c1 = col[e+1], c2 = col[e+2], c3 = col[e+3];
            int c4 = col[e+4], c5 = col[e+5], c6 = col[e+6], c7 = col[e+7];
            float w0 = ew[e+0], w1 = ew[e+1], w2 = ew[e+2], w3 = ew[e+3];
            float w4 = ew[e+4], w5 = ew[e+5], w6 = ew[e+6], w7 = ew[e+7];
            float v0 = h_in[(size_t)c0 * EMBED + lane];
            float v1 = h_in[(size_t)c1 * EMBED + lane];
            float v2 = h_in[(size_t)c2 * EMBED + lane];
            float v3 = h_in[(size_t)c3 * EMBED + lane];
            float v4 = h_in[(size_t)c4 * EMBED + lane];
            float v5 = h_in[(size_t)c5 * EMBED + lane];
            float v6 = h_in[(size_t)c6 * EMBED + lane];
            float v7 = h_in[(size_t)c7 * EMBED + lane];
            acc0 = fmaf(w0, v0, acc0);
            acc1 = fmaf(w1, v1, acc1);
            acc2 = fmaf(w2, v2, acc2);
            acc3 = fmaf(w3, v3, acc3);
            acc0 = fmaf(w4, v4, acc0);
            acc1 = fmaf(w5, v5, acc1);
            acc2 = fmaf(w6, v6, acc2);
            acc3 = fmaf(w7, v7, acc3);
        }
        for (; e + 4 <= t; e += 4) {
            int c0 = col[e+0], c1 = col[e+1], c2 = col[e+2], c3 = col[e+3];
            float w0 = ew[e+0], w1 = ew[e+1], w2 = ew[e+2], w3 = ew[e+3];
            float v0 = h_in[(size_t)c0 * EMBED + lane];
            float v1 = h_in[(size_t)c1 * EMBED + lane];
            float v2 = h_in[(size_t)c2 * EMBED + lane];
            float v3 = h_in[(size_t)c3 * EMBED + lane];
            acc0 = fmaf(w0, v0, acc0);
            acc1 = fmaf(w1, v1, acc1);
            acc2 = fmaf(w2, v2, acc2);
            acc3 = fmaf(w3, v3, acc3);
        }
        for (; e < t; ++e) {
            acc0 = fmaf(ew[e], h_in[(size_t)col[e] * EMBED + lane], acc0);
        }
        float addv = self + ((acc0 + acc1) + (acc2 + acc3));

        float x = bias;
        #pragma unroll
        for (int j = 0; j < 16; ++j) {
            float4 wv = Wr[j];
            x = fmaf(__shfl(addv, 4 * j + 0), wv.x, x);
            x = fmaf(__shfl(addv, 4 * j + 1), wv.y, x);
            x = fmaf(__shfl(addv, 4 * j + 2), wv.z, x);
            x = fmaf(__shfl(addv, 4 * j + 3), wv.w, x);
        }
        x = fmaxf(x, 0.f);

        float ss = x * x;
        #pragma unroll
        for (int off = 32; off > 0; off >>= 1) ss += __shfl_xor(ss, off);
        float nrm = sqrtf(ss);
        float scale = 1.f / fmaxf(nrm, 1e-12f);
        out[(size_t)n * EMBED + lane] = x * scale;
    }
}

extern "C" void kernel_launch(void* const* d_in, const int* in_sizes, int n_in,
                              void* d_out, int out_size, void* d_ws, size_t ws_size,
                              hipStream_t stream) {
    const float* h0   = (const float*)d_in[0];
    const float* ha   = (const float*)d_in[1];
    const float* ta   = (const float*)d_in[2];
    const float* w1   = (const float*)d_in[3];
    const float* b1   = (const float*)d_in[4];
    const float* w2   = (const float*)d_in[5];
    const float* b2   = (const float*)d_in[6];
    const int*   erow = (const int*)d_in[7];
    const int*   ecol = (const int*)d_in[8];

    const int N = in_sizes[0] / EMBED;
    const int E = in_sizes[7];
    float* out = (float*)d_out;

    // workspace layout: row_ptr[N+1] ints, then edge weights[E] floats
    int*   rp = (int*)d_ws;
    size_t rp_bytes = ((size_t)(N + 1) * sizeof(int) + 255) & ~(size_t)255;
    float* ew = (float*)((char*)d_ws + rp_bytes);

    // 1. out[0] = h0
    {
        int n4 = N * EMBED / 4;
        copy_h0_kernel<<<(n4 + 255) / 256, 256, 0, stream>>>(h0, out, n4);
    }
    // 2. CSR row_ptr
    build_rowptr_kernel<<<(E + 255) / 256, 256, 0, stream>>>(erow, rp, E, N);
    // 3. edge logits (one lane/edge)
    edge_logits_kernel<<<(E + 255) / 256, 256, 0, stream>>>(ha, ta, erow, ecol, ew, E);
    // 4. per-node softmax (one wave/node, in-place logits -> weights)
    {
        int waves_per_block = 256 / 64;
        int blocks = (N + waves_per_block - 1) / waves_per_block;
        node_softmax_kernel<<<blocks, 256, 0, stream>>>(rp, ew, N);
    }

    // 5. layer 1: h0 -> out[1];  layer 2: out[1] -> out[2]
    const int blocks = 2048;
    const int totalWaves = blocks * (256 / 64);
    float* out1 = out + (size_t)N * EMBED;
    float* out2 = out + 2 * (size_t)N * EMBED;
    prop_layer_kernel<<<blocks, 256, 0, stream>>>(h0,   w1, b1, ecol, ew, rp, out1, N, totalWaves);
    prop_layer_kernel<<<blocks, 256, 0, stream>>>(out1, w2, b2, ecol, ew, rp, out2, N, totalWaves);
}